// Round 1
// baseline (369.631 us; speedup 1.0000x reference)
//
#include <hip/hip_runtime.h>

#define LAMBD 1.0f

__global__ void deg_kernel(const int* __restrict__ edges, float* __restrict__ deg, int E) {
    int i = blockIdx.x * blockDim.x + threadIdx.x;
    if (i < E) {
        int a = edges[2 * i];
        int b = edges[2 * i + 1];
        atomicAdd(&deg[a], 1.0f);
        atomicAdd(&deg[b], 1.0f);
    }
}

__global__ void scatter_kernel(const int* __restrict__ edges, const float* __restrict__ x,
                               float* __restrict__ nbr, int E) {
    int i = blockIdx.x * blockDim.x + threadIdx.x;
    if (i < E) {
        int a = edges[2 * i];
        int b = edges[2 * i + 1];
        float xa0 = x[3 * a + 0], xa1 = x[3 * a + 1], xa2 = x[3 * a + 2];
        float xb0 = x[3 * b + 0], xb1 = x[3 * b + 1], xb2 = x[3 * b + 2];
        atomicAdd(&nbr[3 * a + 0], xb0);
        atomicAdd(&nbr[3 * a + 1], xb1);
        atomicAdd(&nbr[3 * a + 2], xb2);
        atomicAdd(&nbr[3 * b + 0], xa0);
        atomicAdd(&nbr[3 * b + 1], xa1);
        atomicAdd(&nbr[3 * b + 2], xa2);
    }
}

__global__ void update_kernel(const float* __restrict__ x, const float* __restrict__ nbr,
                              const float* __restrict__ deg, float* __restrict__ y, int n3) {
    int i = blockIdx.x * blockDim.x + threadIdx.x;
    if (i < n3) {
        int vtx = i / 3;
        float d = deg[vtx];
        float inv = 1.0f / fmaxf(d, 1.0f);
        float xv = x[i];
        // match reference arithmetic: x + lambd*(nbr*inv - x)
        y[i] = xv + LAMBD * (nbr[i] * inv - xv);
    }
}

__global__ void faces_kernel(const int* __restrict__ faces, float* __restrict__ out, int n) {
    int i = blockIdx.x * blockDim.x + threadIdx.x;
    if (i < n) {
        out[i] = (float)faces[i];
    }
}

extern "C" void kernel_launch(void* const* d_in, const int* in_sizes, int n_in,
                              void* d_out, int out_size, void* d_ws, size_t ws_size,
                              hipStream_t stream) {
    const float* v     = (const float*)d_in[0];  // [V,3]
    const int*   edges = (const int*)d_in[1];    // [E,2]
    const int*   faces = (const int*)d_in[2];    // [F,3]

    const int V3 = in_sizes[0];      // 3*V
    const int V  = V3 / 3;
    const int E  = in_sizes[1] / 2;
    const int F3 = in_sizes[2];      // 3*F

    float* out_v = (float*)d_out;            // [V,3]
    float* out_f = (float*)d_out + V3;       // [F,3] as floats

    // Workspace layout (floats): deg[V] | nbr[3V] | x1[3V]
    float* deg = (float*)d_ws;
    float* nbr = deg + V;
    float* x1  = nbr + V3;

    const int BS = 256;
    int gE  = (E  + BS - 1) / BS;
    int gV3 = (V3 + BS - 1) / BS;
    int gF3 = (F3 + BS - 1) / BS;

    // zero deg + nbr (ws is poisoned 0xAA before every call)
    hipMemsetAsync(d_ws, 0, (size_t)(V + V3) * sizeof(float), stream);

    deg_kernel<<<gE, BS, 0, stream>>>(edges, deg, E);

    // iteration 1: v -> x1
    scatter_kernel<<<gE, BS, 0, stream>>>(edges, v, nbr, E);
    update_kernel<<<gV3, BS, 0, stream>>>(v, nbr, deg, x1, V3);

    // re-zero nbr for iteration 2
    hipMemsetAsync(nbr, 0, (size_t)V3 * sizeof(float), stream);

    // iteration 2: x1 -> out_v
    scatter_kernel<<<gE, BS, 0, stream>>>(edges, x1, nbr, E);
    update_kernel<<<gV3, BS, 0, stream>>>(x1, nbr, deg, out_v, V3);

    // faces copied as float values
    faces_kernel<<<gF3, BS, 0, stream>>>(faces, out_f, F3);
}

// Round 2
// 129.745 us; speedup vs baseline: 2.8489x; 2.8489x over previous
//
#include <hip/hip_runtime.h>

#define LAMBD 1.0f
#define SCAN_BS 1024

// Per edge: count degree and capture each endpoint's arrival rank (CSR slot).
__global__ void deg_rank_kernel(const int2* __restrict__ edges, int* __restrict__ deg,
                                int* __restrict__ rank2, int E) {
    int i = blockIdx.x * blockDim.x + threadIdx.x;
    if (i < E) {
        int2 e = edges[i];
        rank2[2 * i]     = atomicAdd(&deg[e.x], 1);
        rank2[2 * i + 1] = atomicAdd(&deg[e.y], 1);
    }
}

// Block-level exclusive scan of deg -> offs (without inter-block base), block sums -> bsum.
__global__ void scan_block_kernel(const int* __restrict__ deg, int* __restrict__ offs,
                                  int* __restrict__ bsum, int V) {
    __shared__ int sm[SCAN_BS];
    int t = threadIdx.x;
    int g = blockIdx.x * SCAN_BS + t;
    int v = (g < V) ? deg[g] : 0;
    sm[t] = v;
    __syncthreads();
    for (int d = 1; d < SCAN_BS; d <<= 1) {
        int x = (t >= d) ? sm[t - d] : 0;
        __syncthreads();
        sm[t] += x;
        __syncthreads();
    }
    int incl = sm[t];
    if (g < V) offs[g] = incl - v;          // exclusive, block-local
    if (t == SCAN_BS - 1) bsum[blockIdx.x] = incl;  // block total
}

// Single-block exclusive scan of block sums -> bbase (handles NB up to any size via chunking).
__global__ void scan_partials_kernel(const int* __restrict__ bsum, int* __restrict__ bbase, int NB) {
    __shared__ int sm[SCAN_BS];
    int t = threadIdx.x;
    int run = 0;
    for (int base = 0; base < NB; base += SCAN_BS) {
        int g = base + t;
        int v = (g < NB) ? bsum[g] : 0;
        sm[t] = v;
        __syncthreads();
        for (int d = 1; d < SCAN_BS; d <<= 1) {
            int x = (t >= d) ? sm[t - d] : 0;
            __syncthreads();
            sm[t] += x;
            __syncthreads();
        }
        int incl = sm[t];
        if (g < NB) bbase[g] = run + incl - v;
        int tot = sm[SCAN_BS - 1];
        __syncthreads();   // protect sm before next chunk's write
        run += tot;
    }
}

__global__ void add_base_kernel(int* __restrict__ offs, const int* __restrict__ bbase, int V) {
    int g = blockIdx.x * blockDim.x + threadIdx.x;
    if (g < V) offs[g] += bbase[g / SCAN_BS];
}

// Fill CSR adjacency with plain stores (ranks captured during counting — no atomics).
__global__ void fill_kernel(const int2* __restrict__ edges, const int* __restrict__ rank2,
                            const int* __restrict__ offs, int* __restrict__ adj, int E) {
    int i = blockIdx.x * blockDim.x + threadIdx.x;
    if (i < E) {
        int2 e = edges[i];
        adj[offs[e.x] + rank2[2 * i]]     = e.y;
        adj[offs[e.y] + rank2[2 * i + 1]] = e.x;
    }
}

// One smoothing iteration as a pure gather: y = x + lambd*(nbr_sum/deg - x)
__global__ void gather_kernel(const float* __restrict__ x, const int* __restrict__ offs,
                              const int* __restrict__ deg, const int* __restrict__ adj,
                              float* __restrict__ y, int V) {
    int v = blockIdx.x * blockDim.x + threadIdx.x;
    if (v < V) {
        int o = offs[v];
        int d = deg[v];
        float s0 = 0.f, s1 = 0.f, s2 = 0.f;
        for (int k = 0; k < d; k++) {
            int n = adj[o + k];
            s0 += x[3 * n + 0];
            s1 += x[3 * n + 1];
            s2 += x[3 * n + 2];
        }
        float inv = 1.0f / fmaxf((float)d, 1.0f);
        float x0 = x[3 * v + 0], x1v = x[3 * v + 1], x2 = x[3 * v + 2];
        y[3 * v + 0] = x0  + LAMBD * (s0 * inv - x0);
        y[3 * v + 1] = x1v + LAMBD * (s1 * inv - x1v);
        y[3 * v + 2] = x2  + LAMBD * (s2 * inv - x2);
    }
}

__global__ void faces_kernel(const int* __restrict__ faces, float* __restrict__ out, int n) {
    int i = blockIdx.x * blockDim.x + threadIdx.x;
    if (i < n) out[i] = (float)faces[i];
}

extern "C" void kernel_launch(void* const* d_in, const int* in_sizes, int n_in,
                              void* d_out, int out_size, void* d_ws, size_t ws_size,
                              hipStream_t stream) {
    const float* v      = (const float*)d_in[0];  // [V,3]
    const int2*  edges  = (const int2*)d_in[1];   // [E,2]
    const int*   faces  = (const int*)d_in[2];    // [F,3]

    const int V3 = in_sizes[0];
    const int V  = V3 / 3;
    const int E  = in_sizes[1] / 2;
    const int F3 = in_sizes[2];

    float* out_v = (float*)d_out;
    float* out_f = (float*)d_out + V3;

    const int NB = (V + SCAN_BS - 1) / SCAN_BS;

    // Workspace layout (4B words): deg[V] | offs[V] | bsum[NB] | bbase[NB] | rank2[2E] | adj[2E] | x1[3V]
    int*   deg   = (int*)d_ws;
    int*   offs  = deg + V;
    int*   bsum  = offs + V;
    int*   bbase = bsum + NB;
    int*   rank2 = bbase + NB;
    int*   adj   = rank2 + 2 * E;
    float* x1    = (float*)(adj + 2 * E);

    const int BS = 256;
    int gE  = (E  + BS - 1) / BS;
    int gV  = (V  + BS - 1) / BS;
    int gF3 = (F3 + BS - 1) / BS;

    // Only deg needs zeroing (ws is poisoned before every call); everything else is fully written.
    hipMemsetAsync(deg, 0, (size_t)V * sizeof(int), stream);

    deg_rank_kernel<<<gE, BS, 0, stream>>>(edges, deg, rank2, E);

    scan_block_kernel<<<NB, SCAN_BS, 0, stream>>>(deg, offs, bsum, V);
    scan_partials_kernel<<<1, SCAN_BS, 0, stream>>>(bsum, bbase, NB);
    add_base_kernel<<<gV, BS, 0, stream>>>(offs, bbase, V);

    fill_kernel<<<gE, BS, 0, stream>>>(edges, rank2, offs, adj, E);

    gather_kernel<<<gV, BS, 0, stream>>>(v,  offs, deg, adj, x1,    V);
    gather_kernel<<<gV, BS, 0, stream>>>(x1, offs, deg, adj, out_v, V);

    faces_kernel<<<gF3, BS, 0, stream>>>(faces, out_f, F3);
}

// Round 3
// 105.505 us; speedup vs baseline: 3.5034x; 1.2298x over previous
//
#include <hip/hip_runtime.h>

#define LAMBD 1.0f
#define SCAN_BS 1024

// Combined kernel:
//  threads [0, E]      : a-side boundary detection (edges[:,0] is sorted ascending,
//                        guaranteed by np.unique(axis=0) lexicographic row sort)
//                        + b-side degree count w/ rank capture (i < E)
//  threads (E, E+F3]   : faces -> float copy
__global__ void build_kernel(const int2* __restrict__ edges, int* __restrict__ offs_a,
                             int* __restrict__ deg_b, int* __restrict__ rank,
                             const int* __restrict__ faces, float* __restrict__ out_f,
                             int E, int V, int F3) {
    int i = blockIdx.x * blockDim.x + threadIdx.x;
    if (i <= E) {
        if (i < E) {
            int2 e = edges[i];
            // b-side rank-capturing count (only atomics in the whole pipeline)
            rank[i] = atomicAdd(&deg_b[e.y], 1);
            // a-side boundary: offs_a[v] = i for v in (a[i-1], a[i]]
            int lo = (i == 0) ? 0 : edges[i - 1].x + 1;
            int hi = e.x;
            for (int v = lo; v <= hi; v++) offs_a[v] = i;
        } else {
            // tail: v in (a[E-1], V] -> E   (offs_a has V+1 entries)
            int lo = edges[E - 1].x + 1;
            for (int v = lo; v <= V; v++) offs_a[v] = E;
        }
    } else {
        int j = i - (E + 1);
        if (j < F3) out_f[j] = (float)faces[j];
    }
}

// Block-local exclusive scan of deg_b -> offs_loc; block totals -> bsum.
__global__ void scan_block_kernel(const int* __restrict__ deg, int* __restrict__ offs,
                                  int* __restrict__ bsum, int V) {
    __shared__ int sm[SCAN_BS];
    int t = threadIdx.x;
    int g = blockIdx.x * SCAN_BS + t;
    int v = (g < V) ? deg[g] : 0;
    sm[t] = v;
    __syncthreads();
    for (int d = 1; d < SCAN_BS; d <<= 1) {
        int x = (t >= d) ? sm[t - d] : 0;
        __syncthreads();
        sm[t] += x;
        __syncthreads();
    }
    int incl = sm[t];
    if (g < V) offs[g] = incl - v;
    if (t == SCAN_BS - 1) bsum[blockIdx.x] = incl;
}

// Single-block exclusive scan of block sums -> bbase.
__global__ void scan_partials_kernel(const int* __restrict__ bsum, int* __restrict__ bbase, int NB) {
    __shared__ int sm[SCAN_BS];
    int t = threadIdx.x;
    int run = 0;
    for (int base = 0; base < NB; base += SCAN_BS) {
        int g = base + t;
        int v = (g < NB) ? bsum[g] : 0;
        sm[t] = v;
        __syncthreads();
        for (int d = 1; d < SCAN_BS; d <<= 1) {
            int x = (t >= d) ? sm[t - d] : 0;
            __syncthreads();
            sm[t] += x;
            __syncthreads();
        }
        int incl = sm[t];
        if (g < NB) bbase[g] = run + incl - v;
        int tot = sm[SCAN_BS - 1];
        __syncthreads();
        run += tot;
    }
}

// Fill reverse (b-side) adjacency with plain stores. Global offset = offs_loc + bbase.
__global__ void fill_kernel(const int2* __restrict__ edges, const int* __restrict__ rank,
                            const int* __restrict__ offs_loc, const int* __restrict__ bbase,
                            int* __restrict__ adj_b, int E) {
    int i = blockIdx.x * blockDim.x + threadIdx.x;
    if (i < E) {
        int2 e = edges[i];
        int slot = offs_loc[e.y] + bbase[e.y >> 10] + rank[i];
        adj_b[slot] = e.x;
    }
}

// One smoothing iteration. Neighbors of v:
//   a-side: edges[i].y for i in [offs_a[v], offs_a[v+1])   (sorted edge list, sequential reads)
//   b-side: adj_b[bBeg + k], k in [0, deg_b[v])
__global__ void gather_kernel(const float* __restrict__ x, const int2* __restrict__ edges,
                              const int* __restrict__ offs_a, const int* __restrict__ deg_b,
                              const int* __restrict__ offs_loc, const int* __restrict__ bbase,
                              const int* __restrict__ adj_b, float* __restrict__ y, int V) {
    int v = blockIdx.x * blockDim.x + threadIdx.x;
    if (v < V) {
        int aBeg = offs_a[v], aEnd = offs_a[v + 1];
        int db   = deg_b[v];
        int bBeg = offs_loc[v] + bbase[v >> 10];
        float s0 = 0.f, s1 = 0.f, s2 = 0.f;
        for (int i = aBeg; i < aEnd; i++) {
            int n = edges[i].y;
            s0 += x[3 * n + 0]; s1 += x[3 * n + 1]; s2 += x[3 * n + 2];
        }
        for (int k = 0; k < db; k++) {
            int n = adj_b[bBeg + k];
            s0 += x[3 * n + 0]; s1 += x[3 * n + 1]; s2 += x[3 * n + 2];
        }
        int d = (aEnd - aBeg) + db;
        float inv = 1.0f / fmaxf((float)d, 1.0f);
        float x0 = x[3 * v + 0], x1v = x[3 * v + 1], x2 = x[3 * v + 2];
        y[3 * v + 0] = x0  + LAMBD * (s0 * inv - x0);
        y[3 * v + 1] = x1v + LAMBD * (s1 * inv - x1v);
        y[3 * v + 2] = x2  + LAMBD * (s2 * inv - x2);
    }
}

extern "C" void kernel_launch(void* const* d_in, const int* in_sizes, int n_in,
                              void* d_out, int out_size, void* d_ws, size_t ws_size,
                              hipStream_t stream) {
    const float* v     = (const float*)d_in[0];  // [V,3]
    const int2*  edges = (const int2*)d_in[1];   // [E,2], rows lex-sorted, a<b
    const int*   faces = (const int*)d_in[2];    // [F,3]

    const int V3 = in_sizes[0];
    const int V  = V3 / 3;
    const int E  = in_sizes[1] / 2;
    const int F3 = in_sizes[2];

    float* out_v = (float*)d_out;
    float* out_f = (float*)d_out + V3;

    const int NB = (V + SCAN_BS - 1) / SCAN_BS;

    // ws layout (4B words): deg_b[V] | offs_loc[V] | bsum[NB] | bbase[NB] |
    //                       offs_a[V+1] | rank[E] | adj_b[E] | x1[3V]
    int*   deg_b    = (int*)d_ws;
    int*   offs_loc = deg_b + V;
    int*   bsum     = offs_loc + V;
    int*   bbase    = bsum + NB;
    int*   offs_a   = bbase + NB;
    int*   rank     = offs_a + (V + 1);
    int*   adj_b    = rank + E;
    float* x1       = (float*)(adj_b + E);

    const int BS = 256;
    int T1  = (E + 1) + F3;               // build + faces combined index space
    int g1  = (T1 + BS - 1) / BS;
    int gE  = (E + BS - 1) / BS;
    int gV  = (V + BS - 1) / BS;

    // only deg_b needs zeroing (ws poisoned 0xAA before every call)
    hipMemsetAsync(deg_b, 0, (size_t)V * sizeof(int), stream);

    build_kernel<<<g1, BS, 0, stream>>>(edges, offs_a, deg_b, rank, faces, out_f, E, V, F3);

    scan_block_kernel<<<NB, SCAN_BS, 0, stream>>>(deg_b, offs_loc, bsum, V);
    scan_partials_kernel<<<1, SCAN_BS, 0, stream>>>(bsum, bbase, NB);

    fill_kernel<<<gE, BS, 0, stream>>>(edges, rank, offs_loc, bbase, adj_b, E);

    gather_kernel<<<gV, BS, 0, stream>>>(v,  edges, offs_a, deg_b, offs_loc, bbase, adj_b, x1,    V);
    gather_kernel<<<gV, BS, 0, stream>>>(x1, edges, offs_a, deg_b, offs_loc, bbase, adj_b, out_v, V);
}